// Round 3
// baseline (810.451 us; speedup 1.0000x reference)
//
#include <hip/hip_runtime.h>

typedef __attribute__((ext_vector_type(4))) float f32x4;
typedef __attribute__((ext_vector_type(8))) _Float16 f16x8;

// Cox-de Boor, degree 3, GRID_SIZE=5 -> 8 bases on the extended grid
// [-2.2, 2.2]. Knots use the reference's exact fp32 formula j*0.4f - 1.0f
// (computed as (j-3)*0.4f - 1.0f matching arange(-3..8)*h - 1) so the
// degree-0 indicator comparisons match the reference bit-exactly.
__device__ __forceinline__ void bspline8(float x, float b[8]) {
  float c[11];
#pragma unroll
  for (int j = 0; j < 11; ++j) {
    float t0 = (float)(j - 3) * 0.4f - 1.0f;
    float t1 = (float)(j - 2) * 0.4f - 1.0f;
    c[j] = (x >= t0 && x < t1) ? 1.0f : 0.0f;
  }
#pragma unroll
  for (int k = 1; k <= 3; ++k) {
#pragma unroll
    for (int j = 0; j + k < 11; ++j) {
      float tj   = (float)(j - 3) * 0.4f - 1.0f;
      float tjk  = (float)(j + k - 3) * 0.4f - 1.0f;
      float tj1  = (float)(j - 2) * 0.4f - 1.0f;
      float tjk1 = (float)(j + k - 2) * 0.4f - 1.0f;
      c[j] = (x - tj) * (1.0f / (tjk - tj)) * c[j] +
             (tjk1 - x) * (1.0f / (tjk1 - tj1)) * c[j + 1];
    }
  }
#pragma unroll
  for (int j = 0; j < 8; ++j) b[j] = c[j];
}

// gate_probs[b][e] = softmax_e( x[b,:] . gate_w[e,:] + gate_b[e] ), fp32
__global__ __launch_bounds__(256) void gate_kernel(const float* __restrict__ x,
                                                   const float* __restrict__ gw,
                                                   const float* __restrict__ gb,
                                                   float* __restrict__ gate) {
  const int b = blockIdx.x * 4 + (threadIdx.x >> 6);
  const int lane = threadIdx.x & 63;
  f32x4 x0 = *(const f32x4*)(x + ((size_t)b << 9) + lane * 8);
  f32x4 x1 = *(const f32x4*)(x + ((size_t)b << 9) + lane * 8 + 4);
  float lg[8];
#pragma unroll
  for (int e = 0; e < 8; ++e) {
    f32x4 w0 = *(const f32x4*)(gw + ((size_t)e << 9) + lane * 8);
    f32x4 w1 = *(const f32x4*)(gw + ((size_t)e << 9) + lane * 8 + 4);
    float d = 0.f;
#pragma unroll
    for (int j = 0; j < 4; ++j) d += x0[j] * w0[j] + x1[j] * w1[j];
#pragma unroll
    for (int m = 32; m >= 1; m >>= 1) d += __shfl_xor(d, m, 64);
    lg[e] = d + gb[e];
  }
  float mx = lg[0];
#pragma unroll
  for (int e = 1; e < 8; ++e) mx = fmaxf(mx, lg[e]);
  float p[8], ssum = 0.f;
#pragma unroll
  for (int e = 0; e < 8; ++e) { p[e] = __expf(lg[e] - mx); ssum += p[e]; }
  float mine = 0.f;
#pragma unroll
  for (int e = 0; e < 8; ++e) mine = (lane == e) ? p[e] / ssum : mine;
  if (lane < 8) gate[(size_t)b * 8 + lane] = mine;
}

// W'[row][k] (row = e*512+o, ld=4608), fp16: k<512 -> base_w[row][k];
// k>=512 -> spline_w[row][i][c]*scaler[row][i] at k = 512 + i*8 + c.
__global__ __launch_bounds__(256) void prep_w_kernel(const float* __restrict__ bw,
                                                     const float* __restrict__ sw,
                                                     const float* __restrict__ sc,
                                                     _Float16* __restrict__ W) {
  size_t tid = (size_t)blockIdx.x * 256 + threadIdx.x;
  const size_t NSPL = (size_t)4096 * 512;
  if (tid < NSPL) {
    size_t row = tid >> 9;
    int i = (int)(tid & 511);
    float s = sc[(row << 9) + i];
    const float* sp = sw + (((row << 9) + (size_t)i) << 3);
    f32x4 v0 = *(const f32x4*)sp;
    f32x4 v1 = *(const f32x4*)(sp + 4);
    f16x8 o;
#pragma unroll
    for (int j = 0; j < 4; ++j) { o[j] = (_Float16)(v0[j] * s); o[4 + j] = (_Float16)(v1[j] * s); }
    *(f16x8*)(W + row * 4608 + 512 + (size_t)i * 8) = o;
  } else {
    size_t t2 = tid - NSPL;  // < 4096*64
    size_t row = t2 >> 6;
    int i8 = (int)((t2 & 63) << 3);
    const float* bp = bw + (row << 9) + i8;
    f32x4 v0 = *(const f32x4*)bp;
    f32x4 v1 = *(const f32x4*)(bp + 4);
    f16x8 o;
#pragma unroll
    for (int j = 0; j < 4; ++j) { o[j] = (_Float16)v0[j]; o[4 + j] = (_Float16)v1[j]; }
    *(f16x8*)(W + row * 4608 + i8) = o;
  }
}

// A1[r][k] fp16 for chunk rows: k<512 silu(x), else bases(x_i)[c]
__global__ __launch_bounds__(256) void expand_x_kernel(const float* __restrict__ x,
                                                       _Float16* __restrict__ A1, int chunk0) {
  const int tid = blockIdx.x * 256 + threadIdx.x;
  const int r = tid >> 9;
  const int i = tid & 511;
  const float xv = x[((size_t)(chunk0 + r) << 9) + i];
  const float s = xv / (1.0f + __expf(-xv));
  float bsv[8];
  bspline8(xv, bsv);
  _Float16* drow = A1 + (size_t)r * 4608;
  drow[i] = (_Float16)s;
  f16x8 v;
#pragma unroll
  for (int j = 0; j < 8; ++j) v[j] = (_Float16)bsv[j];
  *(f16x8*)(drow + 512 + (size_t)i * 8) = v;
}

// 128x128 tile GEMM, K=4608, BK=32, 4 waves each 4x4 of mfma_f32_16x16x32_f16.
// A row-major [M][4608]; W row-major [512][4608] (B^T form). MODE 1: epilogue
// expands h -> silu+bases into A2 (layer-2 A, fp16). MODE 2: epilogue
// atomically accumulates gate[b,e]*val into fp32 out (d_out directly).
template <int MODE>
__global__ __launch_bounds__(256) void kan_gemm(const _Float16* __restrict__ Abase,
                                                const _Float16* __restrict__ Wbase,
                                                _Float16* __restrict__ A2out,
                                                float* __restrict__ out_acc,
                                                const float* __restrict__ gate,
                                                int chunk0, int Mc) {
  __shared__ _Float16 As[128 * 32];
  __shared__ _Float16 Bs[128 * 32];
  const int t = threadIdx.x;
  const int z = blockIdx.z;
  const int tileM = blockIdx.x * 128;
  const int tileN = blockIdx.y * 128;

  const _Float16* A = (MODE == 1) ? Abase : (Abase + (size_t)z * Mc * 4608);
  const _Float16* B = Wbase + (size_t)z * 512 * 4608;

  // staging: thread t covers tile row t/4, cols (t%4)*8..+8 (16B)
  const int srow = t >> 2;
  const int scol = (t & 3) * 8;
  const _Float16* gA0 = A + (size_t)(tileM + srow) * 4608 + scol;
  const _Float16* gA1 = A + (size_t)(tileM + 64 + srow) * 4608 + scol;
  const _Float16* gB0 = B + (size_t)(tileN + srow) * 4608 + scol;
  const _Float16* gB1 = B + (size_t)(tileN + 64 + srow) * 4608 + scol;
  _Float16* lA0 = &As[t * 8];
  _Float16* lA1 = &As[2048 + t * 8];
  _Float16* lB0 = &Bs[t * 8];
  _Float16* lB1 = &Bs[2048 + t * 8];

  const int lane = t & 63;
  const int wm = ((t >> 6) & 1) * 64;
  const int wn = ((t >> 6) >> 1) * 64;
  const int l16 = lane & 15;
  const int quad = lane >> 4;

  f32x4 acc[4][4];
#pragma unroll
  for (int i = 0; i < 4; ++i)
#pragma unroll
    for (int j = 0; j < 4; ++j) acc[i][j] = (f32x4){0.f, 0.f, 0.f, 0.f};

  for (int k0 = 0; k0 < 4608; k0 += 32) {
    f16x8 vA0 = *(const f16x8*)(gA0 + k0);
    f16x8 vA1 = *(const f16x8*)(gA1 + k0);
    f16x8 vB0 = *(const f16x8*)(gB0 + k0);
    f16x8 vB1 = *(const f16x8*)(gB1 + k0);
    *(f16x8*)lA0 = vA0;
    *(f16x8*)lA1 = vA1;
    *(f16x8*)lB0 = vB0;
    *(f16x8*)lB1 = vB1;
    __syncthreads();
    f16x8 af[4], bfr[4];
#pragma unroll
    for (int mt = 0; mt < 4; ++mt)
      af[mt] = *(const f16x8*)(&As[(wm + mt * 16 + l16) * 32 + quad * 8]);
#pragma unroll
    for (int nt = 0; nt < 4; ++nt)
      bfr[nt] = *(const f16x8*)(&Bs[(wn + nt * 16 + l16) * 32 + quad * 8]);
#pragma unroll
    for (int mt = 0; mt < 4; ++mt)
#pragma unroll
      for (int nt = 0; nt < 4; ++nt)
        acc[mt][nt] = __builtin_amdgcn_mfma_f32_16x16x32_f16(af[mt], bfr[nt], acc[mt][nt], 0, 0, 0);
    __syncthreads();
  }

  // C/D layout: col = lane&15, row = quad*4 + reg (m89/m91-verified)
  if (MODE == 1) {
    _Float16* dst = A2out + (size_t)z * Mc * 4608;
#pragma unroll
    for (int mt = 0; mt < 4; ++mt) {
#pragma unroll
      for (int r = 0; r < 4; ++r) {
        const int m = tileM + wm + mt * 16 + quad * 4 + r;
        _Float16* drow = dst + (size_t)m * 4608;
#pragma unroll
        for (int nt = 0; nt < 4; ++nt) {
          const int n = tileN + wn + nt * 16 + l16;
          const float h = acc[mt][nt][r];
          const float s = h / (1.0f + __expf(-h));
          float bsv[8];
          bspline8(h, bsv);
          drow[n] = (_Float16)s;
          f16x8 v;
#pragma unroll
          for (int j = 0; j < 8; ++j) v[j] = (_Float16)bsv[j];
          *(f16x8*)(drow + 512 + (size_t)n * 8) = v;
        }
      }
    }
  } else {
#pragma unroll
    for (int mt = 0; mt < 4; ++mt) {
#pragma unroll
      for (int r = 0; r < 4; ++r) {
        const int m = tileM + wm + mt * 16 + quad * 4 + r;
        const float gp = gate[(size_t)(chunk0 + m) * 8 + z];
        float* orow = out_acc + (size_t)(chunk0 + m) * 512;
#pragma unroll
        for (int nt = 0; nt < 4; ++nt) {
          const int n = tileN + wn + nt * 16 + l16;
          atomicAdd(orow + n, gp * acc[mt][nt][r]);
        }
      }
    }
  }
}

extern "C" void kernel_launch(void* const* d_in, const int* in_sizes, int n_in,
                              void* d_out, int out_size, void* d_ws, size_t ws_size,
                              hipStream_t stream) {
  (void)in_sizes; (void)n_in; (void)out_size;
  const float* x   = (const float*)d_in[0];
  const float* gw  = (const float*)d_in[1];
  const float* gb  = (const float*)d_in[2];
  const float* bw1 = (const float*)d_in[3];
  const float* sw1 = (const float*)d_in[4];
  const float* sc1 = (const float*)d_in[5];
  const float* bw2 = (const float*)d_in[6];
  const float* sw2 = (const float*)d_in[7];
  const float* sc2 = (const float*)d_in[8];
  float* out = (float*)d_out;

  const size_t GATE_B = (size_t)4096 * 8 * 4;
  const size_t W_B    = (size_t)8 * 512 * 4608 * 2;  // fp16
  auto al = [](size_t v) { return (v + 255) & ~(size_t)255; };

  // pick largest M-chunk whose A1 + 8x(A2 chunk) fits ws (deterministic per call)
  int Mc = 128;
  const int cand[6] = {4096, 2048, 1024, 512, 256, 128};
  const size_t fixedB = al(GATE_B) + 2 * al(W_B);
  for (int ci = 0; ci < 6; ++ci) {
    size_t need = fixedB + al((size_t)cand[ci] * 4608 * 2) + al((size_t)8 * cand[ci] * 4608 * 2);
    if (need <= ws_size) { Mc = cand[ci]; break; }
  }

  char* p = (char*)d_ws;
  float* gate      = (float*)p; p += al(GATE_B);
  _Float16* W1     = (_Float16*)p; p += al(W_B);
  _Float16* W2     = (_Float16*)p; p += al(W_B);
  _Float16* A1     = (_Float16*)p; p += al((size_t)Mc * 4608 * 2);
  _Float16* A2     = (_Float16*)p;

  // harness poisons d_out with 0xAA before every timed launch — zero it
  hipMemsetAsync(out, 0, (size_t)4096 * 512 * 4, stream);
  gate_kernel<<<1024, 256, 0, stream>>>(x, gw, gb, gate);
  prep_w_kernel<<<9216, 256, 0, stream>>>(bw1, sw1, sc1, W1);
  prep_w_kernel<<<9216, 256, 0, stream>>>(bw2, sw2, sc2, W2);

  for (int c0 = 0; c0 < 4096; c0 += Mc) {
    expand_x_kernel<<<Mc * 2, 256, 0, stream>>>(x, A1, c0);
    dim3 grid(Mc / 128, 4, 8);
    kan_gemm<1><<<grid, 256, 0, stream>>>(A1, W1, A2, nullptr, nullptr, c0, Mc);
    kan_gemm<2><<<grid, 256, 0, stream>>>(A2, W2, nullptr, out, gate, c0, Mc);
  }
}